// Round 9
// baseline (367.980 us; speedup 1.0000x reference)
//
#include <hip/hip_runtime.h>
#include <math.h>

#define N_NODES 50000
#define N_EDGES 800000
#define EP (N_EDGES + N_NODES)   /* 850000 edges incl. self-loops */
#define IN_CH 128
#define HID 64
#define HEADS 4
#define HC (HID * HEADS)         /* 256 */
#define OUT_CH 128
#define NEG_SLOPE 0.2f
#define NSCAN ((N_NODES + 255) / 256)   /* 196 */
#define MTILES (N_NODES / 16)           /* 3125, exact */

typedef __bf16 bf16x8 __attribute__((ext_vector_type(8)));
typedef float  f32x4  __attribute__((ext_vector_type(4)));
typedef unsigned short u16x8 __attribute__((ext_vector_type(8)));

__device__ __forceinline__ float bf2f(unsigned short u) {
    return __uint_as_float(((unsigned)u) << 16);
}
__device__ __forceinline__ unsigned short f2bf(float f) {
    unsigned u = __float_as_uint(f);
    return (unsigned short)((u + 0x7fffu + ((u >> 16) & 1u)) >> 16);
}
__device__ __forceinline__ float lrelu(float v) {
    return v > 0.f ? v : NEG_SLOPE * v;
}
__device__ __forceinline__ bf16x8 ldfrag(const unsigned short* p) {
    uint4 u = *(const uint4*)p;
    return __builtin_bit_cast(bf16x8, u);
}
__device__ __forceinline__ bf16x8 packA(float4 v0, float4 v1) {
    u16x8 t;
    t[0] = f2bf(v0.x); t[1] = f2bf(v0.y); t[2] = f2bf(v0.z); t[3] = f2bf(v0.w);
    t[4] = f2bf(v1.x); t[5] = f2bf(v1.y); t[6] = f2bf(v1.z); t[7] = f2bf(v1.w);
    return __builtin_bit_cast(bf16x8, t);
}

// ================= CSR build =========================================
__global__ void hist_kernel(const int* __restrict__ ei, int* __restrict__ cnt) {
    int e = blockIdx.x * 256 + threadIdx.x;
    if (e >= EP) return;
    int d = (e < N_EDGES) ? ei[N_EDGES + e] : e - N_EDGES;
    atomicAdd(&cnt[d], 1);
}

__global__ void scan1_kernel(const int* __restrict__ cnt,
                             int* __restrict__ row, int* __restrict__ bsum) {
    __shared__ int buf[256];
    int i = blockIdx.x * 256 + threadIdx.x;
    int v = (i < N_NODES) ? cnt[i] : 0;
    buf[threadIdx.x] = v;
    __syncthreads();
#pragma unroll
    for (int off = 1; off < 256; off <<= 1) {
        int t = (threadIdx.x >= off) ? buf[threadIdx.x - off] : 0;
        __syncthreads();
        buf[threadIdx.x] += t;
        __syncthreads();
    }
    if (i < N_NODES) row[i] = buf[threadIdx.x] - v;   // local exclusive
    if (threadIdx.x == 255) bsum[blockIdx.x] = buf[255];
}

__global__ void scan2_kernel(const int* __restrict__ bsum,
                             int* __restrict__ boff, int* __restrict__ rowN) {
    __shared__ int buf[256];
    int tid = threadIdx.x;
    int v = (tid < NSCAN) ? bsum[tid] : 0;
    buf[tid] = v;
    __syncthreads();
#pragma unroll
    for (int off = 1; off < 256; off <<= 1) {
        int t = (tid >= off) ? buf[tid - off] : 0;
        __syncthreads();
        buf[tid] += t;
        __syncthreads();
    }
    if (tid < NSCAN) boff[tid] = buf[tid] - v;        // exclusive
    if (tid == 255) rowN[0] = buf[255];
}

__global__ void scan3_kernel(int* __restrict__ row, const int* __restrict__ boff,
                             int* __restrict__ pos) {
    int i = blockIdx.x * 256 + threadIdx.x;
    if (i >= N_NODES) return;
    int r = row[i] + boff[blockIdx.x];
    row[i] = r;
    pos[i] = r;
}

// scatter + layer-1 edge softmax numerators (runs AFTER gemm1/att)
__global__ void scatter_el1_kernel(const int* __restrict__ ei,
                                   int* __restrict__ pos,
                                   const float4* __restrict__ AS4,
                                   const float4* __restrict__ AD4,
                                   int* __restrict__ adjS, int* __restrict__ adjD,
                                   float4* __restrict__ EL4) {
    int e = blockIdx.x * 256 + threadIdx.x;
    if (e >= EP) return;
    int s, d;
    if (e < N_EDGES) { s = ei[e]; d = ei[N_EDGES + e]; }
    else             { s = d = e - N_EDGES; }
    int p = atomicAdd(&pos[d], 1);
    adjS[p] = s;
    adjD[p] = d;
    float4 a = AS4[s], b = AD4[d];
    float4 o;
    o.x = expf(lrelu(a.x + b.x));
    o.y = expf(lrelu(a.y + b.y));
    o.z = expf(lrelu(a.z + b.z));
    o.w = expf(lrelu(a.w + b.w));
    EL4[p] = o;
}

// ================= weight packing ==========================================
__global__ void pack12_kernel(const float* __restrict__ W1,
                              const float* __restrict__ L1,
                              const float* __restrict__ W2,
                              const float* __restrict__ L2,
                              unsigned short* __restrict__ Bp1,
                              unsigned short* __restrict__ Bp2) {
    int t = blockIdx.x * 256 + threadIdx.x;
    if (t < 8192) {                   // [W1|lin1_w] 128x512, frag=ks*32+nf
        int frag = t >> 6, l = t & 63;
        int ks = frag >> 5, nf = frag & 31;
        int col = nf * 16 + (l & 15);
        int kb = ks * 32 + (l >> 4) * 8;
        unsigned short* o = Bp1 + (size_t)t * 8;
#pragma unroll
        for (int i = 0; i < 8; ++i) {
            int k = kb + i;
            float v = (col < HC) ? W1[k * HC + col] : L1[k * HC + (col - HC)];
            o[i] = f2bf(v);
        }
    } else if (t < 16384) {           // [W2|lin2_w] 256x256, frag=ks*16+nf
        int u = t - 8192;
        int frag = u >> 6, l = u & 63;
        int ks = frag >> 4, nf = frag & 15;
        int col = nf * 16 + (l & 15);
        int kb = ks * 32 + (l >> 4) * 8;
        unsigned short* o = Bp2 + (size_t)u * 8;
#pragma unroll
        for (int i = 0; i < 8; ++i) {
            int k = kb + i;
            float v = (col < OUT_CH) ? W2[k * OUT_CH + col]
                                     : L2[k * OUT_CH + (col - OUT_CH)];
            o[i] = f2bf(v);
        }
    }
}

// ====== MFMA GEMM 1: [H1b | XLb] = x @ [W1|lin1_w], att dots fused =========
__global__ __launch_bounds__(256) void gemm1_mfma(
        const float* __restrict__ x,
        const unsigned short* __restrict__ Bp,
        const float* __restrict__ as1, const float* __restrict__ ad1,
        unsigned short* __restrict__ H1b, unsigned short* __restrict__ XLb,
        float* __restrict__ AS, float* __restrict__ AD) {
    __shared__ float sAS[16][4], sAD[16][4];
    int m0 = blockIdx.x * 16;
    int w = threadIdx.x >> 6, l = threadIdx.x & 63;
    int arow = m0 + (l & 15);
    int koff = (l >> 4) * 8;
    const float* xrow = x + (size_t)arow * IN_CH + koff;
    f32x4 acc[8];
#pragma unroll
    for (int f = 0; f < 8; ++f) acc[f] = (f32x4){0.f, 0.f, 0.f, 0.f};
#pragma unroll
    for (int ks = 0; ks < 4; ++ks) {
        float4 v0 = *(const float4*)(xrow + ks * 32);
        float4 v1 = *(const float4*)(xrow + ks * 32 + 4);
        bf16x8 a = packA(v0, v1);
        const unsigned short* bb = Bp + ((size_t)((ks * 32 + w * 8) * 64 + l)) * 8;
#pragma unroll
        for (int f = 0; f < 8; ++f) {
            bf16x8 b = ldfrag(bb + (size_t)f * 512);
            acc[f] = __builtin_amdgcn_mfma_f32_16x16x32_bf16(a, b, acc[f], 0, 0, 0);
        }
    }
    int g = l >> 4, lc = l & 15;
#pragma unroll
    for (int f = 0; f < 8; ++f) {
        int col = w * 128 + f * 16 + lc;
#pragma unroll
        for (int r = 0; r < 4; ++r) {
            int m = m0 + g * 4 + r;
            float v = acc[f][r];
            if (col < HC) H1b[(size_t)m * HC + col] = f2bf(v);
            else          XLb[(size_t)m * HC + (col - HC)] = f2bf(v);
        }
    }
    // ---- fused attention dots (waves 0,1 hold H1 cols 0..255) ----
    if (w < 2) {
        float ps[4][2], pd[4][2];
#pragma unroll
        for (int r = 0; r < 4; ++r) { ps[r][0]=ps[r][1]=pd[r][0]=pd[r][1]=0.f; }
#pragma unroll
        for (int f = 0; f < 8; ++f) {
            int col = w * 128 + f * 16 + lc;
            float av = as1[col], dv = ad1[col];
            int hp = f >> 2;
#pragma unroll
            for (int r = 0; r < 4; ++r) {
                ps[r][hp] += acc[f][r] * av;
                pd[r][hp] += acc[f][r] * dv;
            }
        }
#pragma unroll
        for (int msk = 1; msk < 16; msk <<= 1)
#pragma unroll
            for (int r = 0; r < 4; ++r) {
                ps[r][0] += __shfl_xor(ps[r][0], msk, 64);
                ps[r][1] += __shfl_xor(ps[r][1], msk, 64);
                pd[r][0] += __shfl_xor(pd[r][0], msk, 64);
                pd[r][1] += __shfl_xor(pd[r][1], msk, 64);
            }
        if (lc == 0)
#pragma unroll
            for (int r = 0; r < 4; ++r) {
                sAS[g * 4 + r][w * 2 + 0] = ps[r][0];
                sAS[g * 4 + r][w * 2 + 1] = ps[r][1];
                sAD[g * 4 + r][w * 2 + 0] = pd[r][0];
                sAD[g * 4 + r][w * 2 + 1] = pd[r][1];
            }
    }
    __syncthreads();
    int t = threadIdx.x;
    if (t < 64)       AS[(m0 + (t >> 2)) * 4 + (t & 3)] = sAS[t >> 2][t & 3];
    else if (t < 128) { int u = t - 64;
                        AD[(m0 + (u >> 2)) * 4 + (u & 3)] = sAD[u >> 2][u & 3]; }
}

// ====== MFMA GEMM 2: [H2b | XL2b] = HBb @ [W2|lin2_w], att dots fused ======
__global__ __launch_bounds__(256) void gemm2_mfma(
        const unsigned short* __restrict__ HBb,
        const unsigned short* __restrict__ Bp,
        const float* __restrict__ as2, const float* __restrict__ ad2,
        unsigned short* __restrict__ H2b, unsigned short* __restrict__ XLb,
        float* __restrict__ AS, float* __restrict__ AD) {
    __shared__ float sAS[16][2], sAD[16][2];
    int m0 = blockIdx.x * 16;
    int w = threadIdx.x >> 6, l = threadIdx.x & 63;
    int arow = m0 + (l & 15);
    int koff = (l >> 4) * 8;
    f32x4 acc[4];
#pragma unroll
    for (int f = 0; f < 4; ++f) acc[f] = (f32x4){0.f, 0.f, 0.f, 0.f};
#pragma unroll
    for (int ks = 0; ks < 8; ++ks) {
        bf16x8 a = ldfrag(HBb + (size_t)arow * HC + ks * 32 + koff);
        const unsigned short* bb = Bp + ((size_t)((ks * 16 + w * 4) * 64 + l)) * 8;
#pragma unroll
        for (int f = 0; f < 4; ++f) {
            bf16x8 b = ldfrag(bb + (size_t)f * 512);
            acc[f] = __builtin_amdgcn_mfma_f32_16x16x32_bf16(a, b, acc[f], 0, 0, 0);
        }
    }
    int g = l >> 4, lc = l & 15;
#pragma unroll
    for (int f = 0; f < 4; ++f) {
        int col = w * 64 + f * 16 + lc;
#pragma unroll
        for (int r = 0; r < 4; ++r) {
            int m = m0 + g * 4 + r;
            float v = acc[f][r];
            if (col < OUT_CH) H2b[(size_t)m * OUT_CH + col] = f2bf(v);
            else              XLb[(size_t)m * OUT_CH + (col - OUT_CH)] = f2bf(v);
        }
    }
    // ---- fused attention dots (waves 0,1 hold H2 cols 0..127) ----
    if (w < 2) {
        float ps[4], pd[4];
#pragma unroll
        for (int r = 0; r < 4; ++r) { ps[r] = 0.f; pd[r] = 0.f; }
#pragma unroll
        for (int f = 0; f < 4; ++f) {
            int col = w * 64 + f * 16 + lc;
            float av = as2[col], dv = ad2[col];
#pragma unroll
            for (int r = 0; r < 4; ++r) {
                ps[r] += acc[f][r] * av;
                pd[r] += acc[f][r] * dv;
            }
        }
#pragma unroll
        for (int msk = 1; msk < 16; msk <<= 1)
#pragma unroll
            for (int r = 0; r < 4; ++r) {
                ps[r] += __shfl_xor(ps[r], msk, 64);
                pd[r] += __shfl_xor(pd[r], msk, 64);
            }
        if (lc == 0)
#pragma unroll
            for (int r = 0; r < 4; ++r) {
                sAS[g * 4 + r][w] = ps[r];
                sAD[g * 4 + r][w] = pd[r];
            }
    }
    __syncthreads();
    int t = threadIdx.x;
    if (t < 16)       AS[m0 + t] = sAS[t][0] + sAS[t][1];
    else if (t < 32)  { int u = t - 16; AD[m0 + u] = sAD[u][0] + sAD[u][1]; }
}

// ============ layer-2 edge softmax numerators ==============================
__global__ void el2_kernel(const int* __restrict__ adjS,
                           const int* __restrict__ adjD,
                           const float* __restrict__ AS,
                           const float* __restrict__ AD,
                           float* __restrict__ EL) {
    int p = blockIdx.x * 256 + threadIdx.x;
    if (p >= EP) return;
    EL[p] = expf(lrelu(AS[adjS[p]] + AD[adjD[p]]));
}

// ======= fused gather layer 1: 4 independent waves per block ===============
// 256 threads = 4 waves; wave handles node blockIdx*4+w; lane j: ch 4j..4j+3
__global__ __launch_bounds__(256) void gather1_kernel(
        const int* __restrict__ row,
        const int* __restrict__ adjS,
        const float4* __restrict__ EL4,
        const unsigned short* __restrict__ H1b,
        const unsigned short* __restrict__ XLb,
        const float* __restrict__ b1,
        const float* __restrict__ l1b,
        unsigned short* __restrict__ HBb) {
    int d = blockIdx.x * 4 + (threadIdx.x >> 6);
    int j = threadIdx.x & 63;
    int hh = j >> 4;
    int beg = row[d], end = row[d + 1];
    // hoist epilogue loads (independent of the edge loop)
    ushort4 xq = ((const ushort4*)XLb)[(size_t)d * 64 + j];
    float4 bb = ((const float4*)b1)[j];
    float4 lb = ((const float4*)l1b)[j];
    const ushort4* Hr = (const ushort4*)H1b;     // row stride 64
    float a0 = 0.f, a1 = 0.f, a2 = 0.f, a3 = 0.f, esum = 0.f;
    int i = beg;
    for (; i + 16 <= end; i += 16) {
        int sa[16]; float ea[16]; ushort4 qa[16];
#pragma unroll
        for (int k = 0; k < 16; ++k) sa[k] = adjS[i + k];
#pragma unroll
        for (int k = 0; k < 16; ++k) {
            float4 t = EL4[i + k];
            ea[k] = hh < 2 ? (hh == 0 ? t.x : t.y) : (hh == 2 ? t.z : t.w);
        }
#pragma unroll
        for (int k = 0; k < 16; ++k) qa[k] = Hr[(size_t)sa[k] * 64 + j];
#pragma unroll
        for (int k = 0; k < 16; ++k) {
            a0 += ea[k] * bf2f(qa[k].x); a1 += ea[k] * bf2f(qa[k].y);
            a2 += ea[k] * bf2f(qa[k].z); a3 += ea[k] * bf2f(qa[k].w);
            esum += ea[k];
        }
    }
    for (; i + 8 <= end; i += 8) {
        int sa[8]; float ea[8]; ushort4 qa[8];
#pragma unroll
        for (int k = 0; k < 8; ++k) sa[k] = adjS[i + k];
#pragma unroll
        for (int k = 0; k < 8; ++k) {
            float4 t = EL4[i + k];
            ea[k] = hh < 2 ? (hh == 0 ? t.x : t.y) : (hh == 2 ? t.z : t.w);
        }
#pragma unroll
        for (int k = 0; k < 8; ++k) qa[k] = Hr[(size_t)sa[k] * 64 + j];
#pragma unroll
        for (int k = 0; k < 8; ++k) {
            a0 += ea[k] * bf2f(qa[k].x); a1 += ea[k] * bf2f(qa[k].y);
            a2 += ea[k] * bf2f(qa[k].z); a3 += ea[k] * bf2f(qa[k].w);
            esum += ea[k];
        }
    }
    for (; i < end; ++i) {
        int s = adjS[i];
        float4 t = EL4[i];
        float e = hh < 2 ? (hh == 0 ? t.x : t.y) : (hh == 2 ? t.z : t.w);
        ushort4 q = Hr[(size_t)s * 64 + j];
        a0 += e * bf2f(q.x); a1 += e * bf2f(q.y);
        a2 += e * bf2f(q.z); a3 += e * bf2f(q.w);
        esum += e;
    }
    float inv = 1.f / (esum + 1e-16f);
    float v0 = a0 * inv + bf2f(xq.x) + bb.x + lb.x;
    float v1 = a1 * inv + bf2f(xq.y) + bb.y + lb.y;
    float v2 = a2 * inv + bf2f(xq.z) + bb.z + lb.z;
    float v3 = a3 * inv + bf2f(xq.w) + bb.w + lb.w;
    v0 = v0 > 0.f ? v0 : expm1f(v0);
    v1 = v1 > 0.f ? v1 : expm1f(v1);
    v2 = v2 > 0.f ? v2 : expm1f(v2);
    v3 = v3 > 0.f ? v3 : expm1f(v3);
    ushort4 o;
    o.x = f2bf(v0); o.y = f2bf(v1); o.z = f2bf(v2); o.w = f2bf(v3);
    ((ushort4*)HBb)[(size_t)d * 64 + j] = o;
}

// ======= fused gather layer 2: 4 independent waves per block ===============
__global__ __launch_bounds__(256) void gather2_kernel(
        const int* __restrict__ row,
        const int* __restrict__ adjS,
        const float* __restrict__ EL,
        const unsigned short* __restrict__ H2b,
        const unsigned short* __restrict__ XLb,
        const float* __restrict__ b2,
        const float* __restrict__ l2b,
        float* __restrict__ out) {
    int d = blockIdx.x * 4 + (threadIdx.x >> 6);
    int l = threadIdx.x & 63;
    int beg = row[d], end = row[d + 1];
    ushort2 xq = ((const ushort2*)XLb)[(size_t)d * 64 + l];
    float2 bb = ((const float2*)b2)[l];
    float2 lb = ((const float2*)l2b)[l];
    const ushort2* Hr = (const ushort2*)H2b;     // row stride 64
    float ax = 0.f, ay = 0.f, esum = 0.f;
    int i = beg;
    for (; i + 16 <= end; i += 16) {
        int sa[16]; float ea[16]; ushort2 qa[16];
#pragma unroll
        for (int k = 0; k < 16; ++k) sa[k] = adjS[i + k];
#pragma unroll
        for (int k = 0; k < 16; ++k) ea[k] = EL[i + k];
#pragma unroll
        for (int k = 0; k < 16; ++k) qa[k] = Hr[(size_t)sa[k] * 64 + l];
#pragma unroll
        for (int k = 0; k < 16; ++k) {
            ax += ea[k] * bf2f(qa[k].x);
            ay += ea[k] * bf2f(qa[k].y);
            esum += ea[k];
        }
    }
    for (; i + 8 <= end; i += 8) {
        int sa[8]; float ea[8]; ushort2 qa[8];
#pragma unroll
        for (int k = 0; k < 8; ++k) sa[k] = adjS[i + k];
#pragma unroll
        for (int k = 0; k < 8; ++k) ea[k] = EL[i + k];
#pragma unroll
        for (int k = 0; k < 8; ++k) qa[k] = Hr[(size_t)sa[k] * 64 + l];
#pragma unroll
        for (int k = 0; k < 8; ++k) {
            ax += ea[k] * bf2f(qa[k].x);
            ay += ea[k] * bf2f(qa[k].y);
            esum += ea[k];
        }
    }
    for (; i < end; ++i) {
        int s = adjS[i];
        float e = EL[i];
        ushort2 q = Hr[(size_t)s * 64 + l];
        ax += e * bf2f(q.x); ay += e * bf2f(q.y);
        esum += e;
    }
    float inv = 1.f / (esum + 1e-16f);
    ((float2*)out)[(size_t)d * 64 + l] =
        make_float2(ax * inv + bf2f(xq.x) + bb.x + lb.x,
                    ay * inv + bf2f(xq.y) + bb.y + lb.y);
}

extern "C" void kernel_launch(void* const* d_in, const int* in_sizes, int n_in,
                              void* d_out, int out_size, void* d_ws, size_t ws_size,
                              hipStream_t stream) {
    const float* x    = (const float*)d_in[0];
    const int*   ei   = (const int*)d_in[1];
    const float* W1   = (const float*)d_in[2];
    const float* as1  = (const float*)d_in[3];
    const float* ad1  = (const float*)d_in[4];
    const float* b1   = (const float*)d_in[5];
    const float* l1w  = (const float*)d_in[6];
    const float* l1b  = (const float*)d_in[7];
    const float* W2   = (const float*)d_in[8];
    const float* as2  = (const float*)d_in[9];
    const float* ad2  = (const float*)d_in[10];
    const float* b2   = (const float*)d_in[11];
    const float* l2w  = (const float*)d_in[12];
    const float* l2b  = (const float*)d_in[13];
    float* out = (float*)d_out;

    // workspace layout (float units)
    float* ws = (float*)d_ws;
    float* fp = ws;
    unsigned short* H1b = (unsigned short*)fp;                  // N*256 bf16
    fp += (size_t)N_NODES * 128;
    unsigned short* XLb = (unsigned short*)fp;                  // N*256 bf16
    fp += (size_t)N_NODES * 128;
    unsigned short* HBb = (unsigned short*)fp;                  // N*256 bf16
    fp += (size_t)N_NODES * 128;
    float* AS1 = fp; fp += (size_t)N_NODES * HEADS;             // 16B-aligned
    float* AD1 = fp; fp += (size_t)N_NODES * HEADS;
    float* AS2 = fp; fp += N_NODES;
    float* AD2 = fp; fp += N_NODES;
    float* EL1 = fp; fp += (size_t)EP * 4;                      // AoS float4
    unsigned short* Bp1 = (unsigned short*)fp; fp += 32768;     // 128KB
    unsigned short* Bp2 = (unsigned short*)fp; fp += 32768;     // 128KB
    int* cnt  = (int*)fp;
    int* row  = cnt + N_NODES;            // N+1
    int* pos  = row + N_NODES + 1;        // N
    int* bsum = pos + N_NODES;            // NSCAN
    int* boff = bsum + NSCAN;             // NSCAN
    int* adjS = boff + NSCAN;             // EP
    int* adjD = adjS + EP;                // EP
    // layer-2 aliases (written only after their layer-1 uses complete)
    unsigned short* H2b = H1b;                                  // N*128 bf16
    unsigned short* XL2b = XLb;                                 // N*128 bf16
    float* EL2 = EL1;                                           // EP

    int nE = (EP + 255) / 256;

    // ---- CSR histogram + scans (independent of GEMM) ----
    hipMemsetAsync(cnt, 0, N_NODES * 4, stream);
    hist_kernel<<<nE, 256, 0, stream>>>(ei, cnt);
    scan1_kernel<<<NSCAN, 256, 0, stream>>>(cnt, row, bsum);
    scan2_kernel<<<1, 256, 0, stream>>>(bsum, boff, row + N_NODES);
    scan3_kernel<<<NSCAN, 256, 0, stream>>>(row, boff, pos);

    // ---- bf16 weights ----
    pack12_kernel<<<64, 256, 0, stream>>>(W1, l1w, W2, l2w, Bp1, Bp2);

    // ---- layer 1 ----
    gemm1_mfma<<<MTILES, 256, 0, stream>>>(x, Bp1, as1, ad1, H1b, XLb, AS1, AD1);
    scatter_el1_kernel<<<nE, 256, 0, stream>>>(ei, pos, (const float4*)AS1,
                                               (const float4*)AD1, adjS, adjD,
                                               (float4*)EL1);
    gather1_kernel<<<N_NODES / 4, 256, 0, stream>>>(row, adjS, (const float4*)EL1,
                                                    H1b, XLb, b1, l1b, HBb);

    // ---- layer 2 ----
    gemm2_mfma<<<MTILES, 256, 0, stream>>>(HBb, Bp2, as2, ad2, H2b, XL2b, AS2, AD2);
    el2_kernel<<<nE, 256, 0, stream>>>(adjS, adjD, AS2, AD2, EL2);
    gather2_kernel<<<N_NODES / 4, 256, 0, stream>>>(row, adjS, EL2, H2b, XL2b,
                                                    b2, l2b, out);
}

// Round 10
// 269.535 us; speedup vs baseline: 1.3652x; 1.3652x over previous
//
#include <hip/hip_runtime.h>
#include <math.h>

#define N_NODES 50000
#define N_EDGES 800000
#define EP (N_EDGES + N_NODES)   /* 850000 edges incl. self-loops */
#define IN_CH 128
#define HID 64
#define HEADS 4
#define HC (HID * HEADS)         /* 256 */
#define OUT_CH 128
#define NEG_SLOPE 0.2f
#define NSCAN ((N_NODES + 255) / 256)   /* 196 */
#define MT32 ((N_NODES + 31) / 32)      /* 1563, tail block has 16 rows */

typedef __bf16 bf16x8 __attribute__((ext_vector_type(8)));
typedef float  f32x4  __attribute__((ext_vector_type(4)));

__device__ __forceinline__ float bf2f(unsigned short u) {
    return __uint_as_float(((unsigned)u) << 16);
}
__device__ __forceinline__ unsigned short f2bf(float f) {
    unsigned u = __float_as_uint(f);
    return (unsigned short)((u + 0x7fffu + ((u >> 16) & 1u)) >> 16);
}
__device__ __forceinline__ float lrelu(float v) {
    return v > 0.f ? v : NEG_SLOPE * v;
}
__device__ __forceinline__ bf16x8 ldfrag(const unsigned short* p) {
    uint4 u = *(const uint4*)p;
    return __builtin_bit_cast(bf16x8, u);
}

// ================= CSR build =========================================
__global__ void hist_kernel(const int* __restrict__ ei, int* __restrict__ cnt) {
    int e = blockIdx.x * 256 + threadIdx.x;
    if (e >= EP) return;
    int d = (e < N_EDGES) ? ei[N_EDGES + e] : e - N_EDGES;
    atomicAdd(&cnt[d], 1);
}

__global__ void scan1_kernel(const int* __restrict__ cnt,
                             int* __restrict__ row, int* __restrict__ bsum) {
    __shared__ int buf[256];
    int i = blockIdx.x * 256 + threadIdx.x;
    int v = (i < N_NODES) ? cnt[i] : 0;
    buf[threadIdx.x] = v;
    __syncthreads();
#pragma unroll
    for (int off = 1; off < 256; off <<= 1) {
        int t = (threadIdx.x >= off) ? buf[threadIdx.x - off] : 0;
        __syncthreads();
        buf[threadIdx.x] += t;
        __syncthreads();
    }
    if (i < N_NODES) row[i] = buf[threadIdx.x] - v;   // local exclusive
    if (threadIdx.x == 255) bsum[blockIdx.x] = buf[255];
}

__global__ void scan2_kernel(const int* __restrict__ bsum,
                             int* __restrict__ boff, int* __restrict__ rowN) {
    __shared__ int buf[256];
    int tid = threadIdx.x;
    int v = (tid < NSCAN) ? bsum[tid] : 0;
    buf[tid] = v;
    __syncthreads();
#pragma unroll
    for (int off = 1; off < 256; off <<= 1) {
        int t = (tid >= off) ? buf[tid - off] : 0;
        __syncthreads();
        buf[tid] += t;
        __syncthreads();
    }
    if (tid < NSCAN) boff[tid] = buf[tid] - v;        // exclusive
    if (tid == 255) rowN[0] = buf[255];
}

__global__ void scan3_kernel(int* __restrict__ row, const int* __restrict__ boff,
                             int* __restrict__ pos) {
    int i = blockIdx.x * 256 + threadIdx.x;
    if (i >= N_NODES) return;
    int r = row[i] + boff[blockIdx.x];
    row[i] = r;
    pos[i] = r;
}

// scatter + layer-1 edge softmax numerators (runs AFTER gemm1)
__global__ void scatter_el1_kernel(const int* __restrict__ ei,
                                   int* __restrict__ pos,
                                   const float4* __restrict__ AS4,
                                   const float4* __restrict__ AD4,
                                   int* __restrict__ adjS, int* __restrict__ adjD,
                                   float4* __restrict__ EL4) {
    int e = blockIdx.x * 256 + threadIdx.x;
    if (e >= EP) return;
    int s, d;
    if (e < N_EDGES) { s = ei[e]; d = ei[N_EDGES + e]; }
    else             { s = d = e - N_EDGES; }
    int p = atomicAdd(&pos[d], 1);
    adjS[p] = s;
    adjD[p] = d;
    float4 a = AS4[s], b = AD4[d];
    float4 o;
    o.x = expf(lrelu(a.x + b.x));
    o.y = expf(lrelu(a.y + b.y));
    o.z = expf(lrelu(a.z + b.z));
    o.w = expf(lrelu(a.w + b.w));
    EL4[p] = o;
}

// ================= weight packing ==========================================
__global__ void pack12_kernel(const float* __restrict__ W1,
                              const float* __restrict__ L1,
                              const float* __restrict__ W2,
                              const float* __restrict__ L2,
                              unsigned short* __restrict__ Bp1,
                              unsigned short* __restrict__ Bp2) {
    int t = blockIdx.x * 256 + threadIdx.x;
    if (t < 8192) {                   // [W1|lin1_w] 128x512, frag=ks*32+nf
        int frag = t >> 6, l = t & 63;
        int ks = frag >> 5, nf = frag & 31;
        int col = nf * 16 + (l & 15);
        int kb = ks * 32 + (l >> 4) * 8;
        unsigned short* o = Bp1 + (size_t)t * 8;
#pragma unroll
        for (int i = 0; i < 8; ++i) {
            int k = kb + i;
            float v = (col < HC) ? W1[k * HC + col] : L1[k * HC + (col - HC)];
            o[i] = f2bf(v);
        }
    } else if (t < 16384) {           // [W2|lin2_w] 256x256, frag=ks*16+nf
        int u = t - 8192;
        int frag = u >> 6, l = u & 63;
        int ks = frag >> 4, nf = frag & 15;
        int col = nf * 16 + (l & 15);
        int kb = ks * 32 + (l >> 4) * 8;
        unsigned short* o = Bp2 + (size_t)u * 8;
#pragma unroll
        for (int i = 0; i < 8; ++i) {
            int k = kb + i;
            float v = (col < OUT_CH) ? W2[k * OUT_CH + col]
                                     : L2[k * OUT_CH + (col - OUT_CH)];
            o[i] = f2bf(v);
        }
    }
}

// ====== MFMA GEMM 1, M=32 tile, LDS-staged A, att dots fused ===============
__global__ __launch_bounds__(256) void gemm1_mfma(
        const float* __restrict__ x,
        const unsigned short* __restrict__ Bp,
        const float* __restrict__ as1, const float* __restrict__ ad1,
        unsigned short* __restrict__ H1b, unsigned short* __restrict__ XLb,
        float* __restrict__ AS, float* __restrict__ AD) {
    __shared__ unsigned short xs[32][136];   // pad: stride 272B, uniform banks
    __shared__ float shAS[32][4], shAD[32][4];
    int m0 = blockIdx.x * 32;
    int tid = threadIdx.x;
    // ---- stage x (32 rows x 128 f32 -> bf16) into LDS, 8 thr/row ----
    {
        int srow = tid >> 3, cg = (tid & 7) * 16;
        int grow = m0 + srow;
        ushort4 o0 = {0,0,0,0}, o1 = {0,0,0,0}, o2 = {0,0,0,0}, o3 = {0,0,0,0};
        if (grow < N_NODES) {
            const float4* src = (const float4*)(x + (size_t)grow * IN_CH + cg);
            float4 v0 = src[0], v1 = src[1], v2 = src[2], v3 = src[3];
            o0 = make_ushort4(f2bf(v0.x), f2bf(v0.y), f2bf(v0.z), f2bf(v0.w));
            o1 = make_ushort4(f2bf(v1.x), f2bf(v1.y), f2bf(v1.z), f2bf(v1.w));
            o2 = make_ushort4(f2bf(v2.x), f2bf(v2.y), f2bf(v2.z), f2bf(v2.w));
            o3 = make_ushort4(f2bf(v3.x), f2bf(v3.y), f2bf(v3.z), f2bf(v3.w));
        }
        *(ushort4*)&xs[srow][cg + 0]  = o0;
        *(ushort4*)&xs[srow][cg + 4]  = o1;
        *(ushort4*)&xs[srow][cg + 8]  = o2;
        *(ushort4*)&xs[srow][cg + 12] = o3;
    }
    __syncthreads();
    int w = tid >> 6, l = tid & 63;
    int lc = l & 15, g = l >> 4;         // lc: col-in-frag / A-row; g: k-group
    f32x4 acc0[8], acc1[8];
#pragma unroll
    for (int f = 0; f < 8; ++f) {
        acc0[f] = (f32x4){0.f, 0.f, 0.f, 0.f};
        acc1[f] = (f32x4){0.f, 0.f, 0.f, 0.f};
    }
#pragma unroll
    for (int ks = 0; ks < 4; ++ks) {
        bf16x8 a0 = ldfrag(&xs[lc][ks * 32 + g * 8]);
        bf16x8 a1 = ldfrag(&xs[16 + lc][ks * 32 + g * 8]);
        const unsigned short* bb = Bp + ((size_t)((ks * 32 + w * 8) * 64 + l)) * 8;
#pragma unroll
        for (int f = 0; f < 8; ++f) {
            bf16x8 b = ldfrag(bb + (size_t)f * 512);
            acc0[f] = __builtin_amdgcn_mfma_f32_16x16x32_bf16(a0, b, acc0[f], 0, 0, 0);
            acc1[f] = __builtin_amdgcn_mfma_f32_16x16x32_bf16(a1, b, acc1[f], 0, 0, 0);
        }
    }
    // ---- stores (C/D: col=lane&15, row=(lane>>4)*4+r) ----
#pragma unroll
    for (int f = 0; f < 8; ++f) {
        int col = w * 128 + f * 16 + lc;
#pragma unroll
        for (int r = 0; r < 4; ++r) {
            int m = m0 + g * 4 + r;                       // sub 0: always valid
            float v = acc0[f][r];
            if (col < HC) H1b[(size_t)m * HC + col] = f2bf(v);
            else          XLb[(size_t)m * HC + (col - HC)] = f2bf(v);
            int m2 = m0 + 16 + g * 4 + r;                 // sub 1: tail guard
            if (m2 < N_NODES) {
                float v2 = acc1[f][r];
                if (col < HC) H1b[(size_t)m2 * HC + col] = f2bf(v2);
                else          XLb[(size_t)m2 * HC + (col - HC)] = f2bf(v2);
            }
        }
    }
    // ---- fused attention dots (waves 0,1 hold H1 cols 0..255) ----
    if (w < 2) {
        // sub-tile 0
        {
            float ps[4][2], pd[4][2];
#pragma unroll
            for (int r = 0; r < 4; ++r) { ps[r][0]=ps[r][1]=pd[r][0]=pd[r][1]=0.f; }
#pragma unroll
            for (int f = 0; f < 8; ++f) {
                int col = w * 128 + f * 16 + lc;
                float av = as1[col], dv = ad1[col];
                int hp = f >> 2;
#pragma unroll
                for (int r = 0; r < 4; ++r) {
                    ps[r][hp] += acc0[f][r] * av;
                    pd[r][hp] += acc0[f][r] * dv;
                }
            }
#pragma unroll
            for (int msk = 1; msk < 16; msk <<= 1)
#pragma unroll
                for (int r = 0; r < 4; ++r) {
                    ps[r][0] += __shfl_xor(ps[r][0], msk, 64);
                    ps[r][1] += __shfl_xor(ps[r][1], msk, 64);
                    pd[r][0] += __shfl_xor(pd[r][0], msk, 64);
                    pd[r][1] += __shfl_xor(pd[r][1], msk, 64);
                }
            if (lc == 0)
#pragma unroll
                for (int r = 0; r < 4; ++r) {
                    shAS[g * 4 + r][w * 2 + 0] = ps[r][0];
                    shAS[g * 4 + r][w * 2 + 1] = ps[r][1];
                    shAD[g * 4 + r][w * 2 + 0] = pd[r][0];
                    shAD[g * 4 + r][w * 2 + 1] = pd[r][1];
                }
        }
        // sub-tile 1
        {
            float ps[4][2], pd[4][2];
#pragma unroll
            for (int r = 0; r < 4; ++r) { ps[r][0]=ps[r][1]=pd[r][0]=pd[r][1]=0.f; }
#pragma unroll
            for (int f = 0; f < 8; ++f) {
                int col = w * 128 + f * 16 + lc;
                float av = as1[col], dv = ad1[col];
                int hp = f >> 2;
#pragma unroll
                for (int r = 0; r < 4; ++r) {
                    ps[r][hp] += acc1[f][r] * av;
                    pd[r][hp] += acc1[f][r] * dv;
                }
            }
#pragma unroll
            for (int msk = 1; msk < 16; msk <<= 1)
#pragma unroll
                for (int r = 0; r < 4; ++r) {
                    ps[r][0] += __shfl_xor(ps[r][0], msk, 64);
                    ps[r][1] += __shfl_xor(ps[r][1], msk, 64);
                    pd[r][0] += __shfl_xor(pd[r][0], msk, 64);
                    pd[r][1] += __shfl_xor(pd[r][1], msk, 64);
                }
            if (lc == 0)
#pragma unroll
                for (int r = 0; r < 4; ++r) {
                    shAS[16 + g * 4 + r][w * 2 + 0] = ps[r][0];
                    shAS[16 + g * 4 + r][w * 2 + 1] = ps[r][1];
                    shAD[16 + g * 4 + r][w * 2 + 0] = pd[r][0];
                    shAD[16 + g * 4 + r][w * 2 + 1] = pd[r][1];
                }
        }
    }
    __syncthreads();
    if (tid < 128) {
        int rr = tid >> 2, hd = tid & 3;
        int m = m0 + rr;
        if (m < N_NODES) AS[m * 4 + hd] = shAS[rr][hd];
    } else {
        int u = tid - 128, rr = u >> 2, hd = u & 3;
        int m = m0 + rr;
        if (m < N_NODES) AD[m * 4 + hd] = shAD[rr][hd];
    }
}

// ====== MFMA GEMM 2, M=32 tile, LDS-staged A, att dots fused ===============
__global__ __launch_bounds__(256) void gemm2_mfma(
        const unsigned short* __restrict__ HBb,
        const unsigned short* __restrict__ Bp,
        const float* __restrict__ as2, const float* __restrict__ ad2,
        unsigned short* __restrict__ H2b, unsigned short* __restrict__ XLb,
        float* __restrict__ AS, float* __restrict__ AD) {
    __shared__ unsigned short hs[32][264];   // pad: stride 528B
    __shared__ float shAS[32][2], shAD[32][2];
    int m0 = blockIdx.x * 32;
    int tid = threadIdx.x;
    // ---- stage HBb (32 rows x 256 bf16) into LDS, 8 thr/row ----
    {
        int srow = tid >> 3, cg = (tid & 7) * 32;
        int grow = m0 + srow;
        ushort4 z = {0,0,0,0};
        ushort4 q0 = z, q1 = z, q2 = z, q3 = z;
        if (grow < N_NODES) {
            const ushort4* src = (const ushort4*)(HBb + (size_t)grow * HC + cg);
            q0 = src[0]; q1 = src[1]; q2 = src[2]; q3 = src[3];
        }
        *(ushort4*)&hs[srow][cg + 0]  = q0;
        *(ushort4*)&hs[srow][cg + 4]  = q1;
        *(ushort4*)&hs[srow][cg + 8]  = q2;
        *(ushort4*)&hs[srow][cg + 12] = q3;
        // second 32-byte half
        ushort4 q4 = z, q5 = z, q6 = z, q7 = z;
        if (grow < N_NODES) {
            const ushort4* src = (const ushort4*)(HBb + (size_t)grow * HC + cg + 16);
            q4 = src[0]; q5 = src[1]; q6 = src[2]; q7 = src[3];
        }
        *(ushort4*)&hs[srow][cg + 16] = q4;
        *(ushort4*)&hs[srow][cg + 20] = q5;
        *(ushort4*)&hs[srow][cg + 24] = q6;
        *(ushort4*)&hs[srow][cg + 28] = q7;
    }
    __syncthreads();
    int w = tid >> 6, l = tid & 63;
    int lc = l & 15, g = l >> 4;
    f32x4 acc0[4], acc1[4];
#pragma unroll
    for (int f = 0; f < 4; ++f) {
        acc0[f] = (f32x4){0.f, 0.f, 0.f, 0.f};
        acc1[f] = (f32x4){0.f, 0.f, 0.f, 0.f};
    }
#pragma unroll
    for (int ks = 0; ks < 8; ++ks) {
        bf16x8 a0 = ldfrag(&hs[lc][ks * 32 + g * 8]);
        bf16x8 a1 = ldfrag(&hs[16 + lc][ks * 32 + g * 8]);
        const unsigned short* bb = Bp + ((size_t)((ks * 16 + w * 4) * 64 + l)) * 8;
#pragma unroll
        for (int f = 0; f < 4; ++f) {
            bf16x8 b = ldfrag(bb + (size_t)f * 512);
            acc0[f] = __builtin_amdgcn_mfma_f32_16x16x32_bf16(a0, b, acc0[f], 0, 0, 0);
            acc1[f] = __builtin_amdgcn_mfma_f32_16x16x32_bf16(a1, b, acc1[f], 0, 0, 0);
        }
    }
#pragma unroll
    for (int f = 0; f < 4; ++f) {
        int col = w * 64 + f * 16 + lc;
#pragma unroll
        for (int r = 0; r < 4; ++r) {
            int m = m0 + g * 4 + r;
            float v = acc0[f][r];
            if (col < OUT_CH) H2b[(size_t)m * OUT_CH + col] = f2bf(v);
            else              XLb[(size_t)m * OUT_CH + (col - OUT_CH)] = f2bf(v);
            int m2 = m0 + 16 + g * 4 + r;
            if (m2 < N_NODES) {
                float v2 = acc1[f][r];
                if (col < OUT_CH) H2b[(size_t)m2 * OUT_CH + col] = f2bf(v2);
                else              XLb[(size_t)m2 * OUT_CH + (col - OUT_CH)] = f2bf(v2);
            }
        }
    }
    // ---- fused attention dots (waves 0,1 hold H2 cols 0..127) ----
    if (w < 2) {
        {
            float ps[4], pd[4];
#pragma unroll
            for (int r = 0; r < 4; ++r) { ps[r] = 0.f; pd[r] = 0.f; }
#pragma unroll
            for (int f = 0; f < 4; ++f) {
                int col = w * 64 + f * 16 + lc;
                float av = as2[col], dv = ad2[col];
#pragma unroll
                for (int r = 0; r < 4; ++r) {
                    ps[r] += acc0[f][r] * av;
                    pd[r] += acc0[f][r] * dv;
                }
            }
#pragma unroll
            for (int msk = 1; msk < 16; msk <<= 1)
#pragma unroll
                for (int r = 0; r < 4; ++r) {
                    ps[r] += __shfl_xor(ps[r], msk, 64);
                    pd[r] += __shfl_xor(pd[r], msk, 64);
                }
            if (lc == 0)
#pragma unroll
                for (int r = 0; r < 4; ++r) {
                    shAS[g * 4 + r][w] = ps[r];
                    shAD[g * 4 + r][w] = pd[r];
                }
        }
        {
            float ps[4], pd[4];
#pragma unroll
            for (int r = 0; r < 4; ++r) { ps[r] = 0.f; pd[r] = 0.f; }
#pragma unroll
            for (int f = 0; f < 4; ++f) {
                int col = w * 64 + f * 16 + lc;
                float av = as2[col], dv = ad2[col];
#pragma unroll
                for (int r = 0; r < 4; ++r) {
                    ps[r] += acc1[f][r] * av;
                    pd[r] += acc1[f][r] * dv;
                }
            }
#pragma unroll
            for (int msk = 1; msk < 16; msk <<= 1)
#pragma unroll
                for (int r = 0; r < 4; ++r) {
                    ps[r] += __shfl_xor(ps[r], msk, 64);
                    pd[r] += __shfl_xor(pd[r], msk, 64);
                }
            if (lc == 0)
#pragma unroll
                for (int r = 0; r < 4; ++r) {
                    shAS[16 + g * 4 + r][w] = ps[r];
                    shAD[16 + g * 4 + r][w] = pd[r];
                }
        }
    }
    __syncthreads();
    if (tid < 32) {
        int m = m0 + tid;
        if (m < N_NODES) AS[m] = shAS[tid][0] + shAS[tid][1];
    } else if (tid < 64) {
        int u = tid - 32;
        int m = m0 + u;
        if (m < N_NODES) AD[m] = shAD[u][0] + shAD[u][1];
    }
}

// ============ layer-2 edge softmax numerators ==============================
__global__ void el2_kernel(const int* __restrict__ adjS,
                           const int* __restrict__ adjD,
                           const float* __restrict__ AS,
                           const float* __restrict__ AD,
                           float* __restrict__ EL) {
    int p = blockIdx.x * 256 + threadIdx.x;
    if (p >= EP) return;
    EL[p] = expf(lrelu(AS[adjS[p]] + AD[adjD[p]]));
}

// ======= fused gather layer 1 (round-6 proven form) ========================
// 64 threads, one dst node; lane j covers channels 4j..4j+3, head j>>4
__global__ void gather1_kernel(const int* __restrict__ row,
                               const int* __restrict__ adjS,
                               const float4* __restrict__ EL4,
                               const unsigned short* __restrict__ H1b,
                               const unsigned short* __restrict__ XLb,
                               const float* __restrict__ b1,
                               const float* __restrict__ l1b,
                               unsigned short* __restrict__ HBb) {
    int d = blockIdx.x, j = threadIdx.x;
    int hh = j >> 4;
    int beg = row[d], end = row[d + 1];
    const ushort4* Hr = (const ushort4*)H1b;     // row stride 64
    float a0 = 0.f, a1 = 0.f, a2 = 0.f, a3 = 0.f, esum = 0.f;
    int i = beg;
    for (; i + 8 <= end; i += 8) {
        int sa[8]; float ea[8]; ushort4 qa[8];
#pragma unroll
        for (int k = 0; k < 8; ++k) sa[k] = adjS[i + k];
#pragma unroll
        for (int k = 0; k < 8; ++k) {
            float4 t = EL4[i + k];
            ea[k] = hh < 2 ? (hh == 0 ? t.x : t.y) : (hh == 2 ? t.z : t.w);
        }
#pragma unroll
        for (int k = 0; k < 8; ++k) qa[k] = Hr[(size_t)sa[k] * 64 + j];
#pragma unroll
        for (int k = 0; k < 8; ++k) {
            a0 += ea[k] * bf2f(qa[k].x); a1 += ea[k] * bf2f(qa[k].y);
            a2 += ea[k] * bf2f(qa[k].z); a3 += ea[k] * bf2f(qa[k].w);
            esum += ea[k];
        }
    }
    for (; i < end; ++i) {
        int s = adjS[i];
        float4 t = EL4[i];
        float e = hh < 2 ? (hh == 0 ? t.x : t.y) : (hh == 2 ? t.z : t.w);
        ushort4 q = Hr[(size_t)s * 64 + j];
        a0 += e * bf2f(q.x); a1 += e * bf2f(q.y);
        a2 += e * bf2f(q.z); a3 += e * bf2f(q.w);
        esum += e;
    }
    float inv = 1.f / (esum + 1e-16f);
    ushort4 xq = ((const ushort4*)XLb)[(size_t)d * 64 + j];
    float4 bb = ((const float4*)b1)[j];
    float4 lb = ((const float4*)l1b)[j];
    float v0 = a0 * inv + bf2f(xq.x) + bb.x + lb.x;
    float v1 = a1 * inv + bf2f(xq.y) + bb.y + lb.y;
    float v2 = a2 * inv + bf2f(xq.z) + bb.z + lb.z;
    float v3 = a3 * inv + bf2f(xq.w) + bb.w + lb.w;
    v0 = v0 > 0.f ? v0 : expm1f(v0);
    v1 = v1 > 0.f ? v1 : expm1f(v1);
    v2 = v2 > 0.f ? v2 : expm1f(v2);
    v3 = v3 > 0.f ? v3 : expm1f(v3);
    ushort4 o;
    o.x = f2bf(v0); o.y = f2bf(v1); o.z = f2bf(v2); o.w = f2bf(v3);
    ((ushort4*)HBb)[(size_t)d * 64 + j] = o;
}

// ======= fused gather layer 2 (round-6 proven form) ========================
__global__ void gather2_kernel(const int* __restrict__ row,
                               const int* __restrict__ adjS,
                               const float* __restrict__ EL,
                               const unsigned short* __restrict__ H2b,
                               const unsigned short* __restrict__ XLb,
                               const float* __restrict__ b2,
                               const float* __restrict__ l2b,
                               float* __restrict__ out) {
    int d = blockIdx.x, l = threadIdx.x;
    int beg = row[d], end = row[d + 1];
    const ushort2* Hr = (const ushort2*)H2b;     // row stride 64
    float ax = 0.f, ay = 0.f, esum = 0.f;
    int i = beg;
    for (; i + 8 <= end; i += 8) {
        int sa[8]; float ea[8]; ushort2 qa[8];
#pragma unroll
        for (int k = 0; k < 8; ++k) sa[k] = adjS[i + k];
#pragma unroll
        for (int k = 0; k < 8; ++k) ea[k] = EL[i + k];
#pragma unroll
        for (int k = 0; k < 8; ++k) qa[k] = Hr[(size_t)sa[k] * 64 + l];
#pragma unroll
        for (int k = 0; k < 8; ++k) {
            ax += ea[k] * bf2f(qa[k].x);
            ay += ea[k] * bf2f(qa[k].y);
            esum += ea[k];
        }
    }
    for (; i < end; ++i) {
        int s = adjS[i];
        float e = EL[i];
        ushort2 q = Hr[(size_t)s * 64 + l];
        ax += e * bf2f(q.x); ay += e * bf2f(q.y);
        esum += e;
    }
    float inv = 1.f / (esum + 1e-16f);
    ushort2 xq = ((const ushort2*)XLb)[(size_t)d * 64 + l];
    float2 bb = ((const float2*)b2)[l];
    float2 lb = ((const float2*)l2b)[l];
    ((float2*)out)[(size_t)d * 64 + l] =
        make_float2(ax * inv + bf2f(xq.x) + bb.x + lb.x,
                    ay * inv + bf2f(xq.y) + bb.y + lb.y);
}

extern "C" void kernel_launch(void* const* d_in, const int* in_sizes, int n_in,
                              void* d_out, int out_size, void* d_ws, size_t ws_size,
                              hipStream_t stream) {
    const float* x    = (const float*)d_in[0];
    const int*   ei   = (const int*)d_in[1];
    const float* W1   = (const float*)d_in[2];
    const float* as1  = (const float*)d_in[3];
    const float* ad1  = (const float*)d_in[4];
    const float* b1   = (const float*)d_in[5];
    const float* l1w  = (const float*)d_in[6];
    const float* l1b  = (const float*)d_in[7];
    const float* W2   = (const float*)d_in[8];
    const float* as2  = (const float*)d_in[9];
    const float* ad2  = (const float*)d_in[10];
    const float* b2   = (const float*)d_in[11];
    const float* l2w  = (const float*)d_in[12];
    const float* l2b  = (const float*)d_in[13];
    float* out = (float*)d_out;

    // workspace layout (float units)
    float* ws = (float*)d_ws;
    float* fp = ws;
    unsigned short* H1b = (unsigned short*)fp;                  // N*256 bf16
    fp += (size_t)N_NODES * 128;
    unsigned short* XLb = (unsigned short*)fp;                  // N*256 bf16
    fp += (size_t)N_NODES * 128;
    unsigned short* HBb = (unsigned short*)fp;                  // N*256 bf16
    fp += (size_t)N_NODES * 128;
    float* AS1 = fp; fp += (size_t)N_NODES * HEADS;             // 16B-aligned
    float* AD1 = fp; fp += (size_t)N_NODES * HEADS;
    float* AS2 = fp; fp += N_NODES;
    float* AD2 = fp; fp += N_NODES;
    float* EL1 = fp; fp += (size_t)EP * 4;                      // AoS float4
    unsigned short* Bp1 = (unsigned short*)fp; fp += 32768;     // 128KB
    unsigned short* Bp2 = (unsigned short*)fp; fp += 32768;     // 128KB
    int* cnt  = (int*)fp;
    int* row  = cnt + N_NODES;            // N+1
    int* pos  = row + N_NODES + 1;        // N
    int* bsum = pos + N_NODES;            // NSCAN
    int* boff = bsum + NSCAN;             // NSCAN
    int* adjS = boff + NSCAN;             // EP
    int* adjD = adjS + EP;                // EP
    // layer-2 aliases (written only after their layer-1 uses complete)
    unsigned short* H2b = H1b;                                  // N*128 bf16
    unsigned short* XL2b = XLb;                                 // N*128 bf16
    float* EL2 = EL1;                                           // EP

    int nE = (EP + 255) / 256;

    // ---- CSR histogram + scans (independent of GEMM) ----
    hipMemsetAsync(cnt, 0, N_NODES * 4, stream);
    hist_kernel<<<nE, 256, 0, stream>>>(ei, cnt);
    scan1_kernel<<<NSCAN, 256, 0, stream>>>(cnt, row, bsum);
    scan2_kernel<<<1, 256, 0, stream>>>(bsum, boff, row + N_NODES);
    scan3_kernel<<<NSCAN, 256, 0, stream>>>(row, boff, pos);

    // ---- bf16 weights ----
    pack12_kernel<<<64, 256, 0, stream>>>(W1, l1w, W2, l2w, Bp1, Bp2);

    // ---- layer 1 ----
    gemm1_mfma<<<MT32, 256, 0, stream>>>(x, Bp1, as1, ad1, H1b, XLb, AS1, AD1);
    scatter_el1_kernel<<<nE, 256, 0, stream>>>(ei, pos, (const float4*)AS1,
                                               (const float4*)AD1, adjS, adjD,
                                               (float4*)EL1);
    gather1_kernel<<<N_NODES, 64, 0, stream>>>(row, adjS, (const float4*)EL1,
                                               H1b, XLb, b1, l1b, HBb);

    // ---- layer 2 ----
    gemm2_mfma<<<MT32, 256, 0, stream>>>(HBb, Bp2, as2, ad2, H2b, XL2b, AS2, AD2);
    el2_kernel<<<nE, 256, 0, stream>>>(adjS, adjD, AS2, AD2, EL2);
    gather2_kernel<<<N_NODES, 64, 0, stream>>>(row, adjS, EL2, H2b, XL2b,
                                               b2, l2b, out);
}